// Round 6
// baseline (212.808 us; speedup 1.0000x reference)
//
#include <hip/hip_runtime.h>
#include <hip/hip_bf16.h>

typedef __attribute__((ext_vector_type(8))) short bs8;
typedef __attribute__((ext_vector_type(4))) short bs4;
typedef __attribute__((ext_vector_type(4))) float f32x4;

#define HID 64
#define FEATN 32
#define NT 16   // tiles of 16 samples per wave

static __device__ __forceinline__ short f2bf(float f) {
    __hip_bfloat16 h = __float2bfloat16(f);
    return __builtin_bit_cast(short, h);
}

#if defined(__HIP_DEVICE_COMPILE__)
#define MFMA16(a, b, c) __builtin_amdgcn_mfma_f32_16x16x16bf16_1k(a, b, c, 0, 0, 0)
#else
#define MFMA16(a, b, c) (c)
#endif

// Layer 1 (transposed): h^T = W1^T x feats^T via 4x mfma_f32_16x16x32_bf16;
// C-layout (lane holds h[16j+4g+r][sample=row]) IS the B-frag of 16x16x16.
// Layer 2: 4 chained mfma_16x16x16_bf16 with A = W2^T (rows>=4 zero),
// b2 in C-init; outputs land on g==0 lanes.
// Occupancy is the lever this round: VGPR<=64 -> 8 waves/EU (32/CU) to keep
// ~2x more random-gather misses in flight per CU.
__global__ __launch_bounds__(256, 8) void plen_fused(
    const float* __restrict__ pos,
    const float* __restrict__ table,
    const float* __restrict__ W1,
    const float* __restrict__ b1,
    const float* __restrict__ W2,
    const float* __restrict__ b2,
    float* __restrict__ out,
    int batch)
{
    const int lane = threadIdx.x & 63;
    const int row  = lane & 15;
    const int g    = lane >> 4;

    // ---- static weight fragments ----
    bs8   w1f[4];
    f32x4 bias1v[4];
    bs4   w2tf[4];
#pragma unroll
    for (int j = 0; j < 4; ++j) {
#pragma unroll
        for (int i = 0; i < 8; ++i)
            w1f[j][i] = f2bf(W1[(g * 8 + i) * HID + j * 16 + row]);
        bias1v[j] = *(const f32x4*)(b1 + j * 16 + g * 4);
#pragma unroll
        for (int i = 0; i < 4; ++i)
            w2tf[j][i] = (row < 4) ? f2bf(W2[(j * 16 + g * 4 + i) * 4 + row]) : (short)0;
    }
    f32x4 oinit;
    if (g == 0) oinit = *(const f32x4*)b2;
    else        oinit = (f32x4){0.f, 0.f, 0.f, 0.f};

    const int wave_id = blockIdx.x * 4 + (threadIdx.x >> 6);
    const int chunk   = wave_id * (NT * 16);
    const size_t dns_base = (size_t)batch * 3;

    auto loadpos = [&](int t, float& x, float& y, float& z) {
        const int tt = t < NT ? t : NT - 1;          // clamp redundant prefetch
        const float* pp = pos + (size_t)(chunk + tt * 16 + row) * 3;
        x = pp[0]; y = pp[1]; z = pp[2];
    };
    auto issue_gather = [&](float x, float y, float z, f32x4& A, f32x4& B) {
        const unsigned ix = (unsigned)(int)(x * 128.0f);
        const unsigned iy = (unsigned)(int)(y * 128.0f);
        const unsigned iz = (unsigned)(int)(z * 128.0f);
        const unsigned flat = (ix << 14) | (iy << 7) | iz;
        const float* rp = table + (size_t)flat * FEATN + g * 8;
        A = *(const f32x4*)rp;
        B = *(const f32x4*)(rp + 4);
    };
    auto compute = [&](int sbase, f32x4 f0, f32x4 f1) {
        bs8 af;
        af[0] = f2bf(f0[0]); af[1] = f2bf(f0[1]);
        af[2] = f2bf(f0[2]); af[3] = f2bf(f0[3]);
        af[4] = f2bf(f1[0]); af[5] = f2bf(f1[1]);
        af[6] = f2bf(f1[2]); af[7] = f2bf(f1[3]);

        f32x4 acc[4];
#pragma unroll
        for (int j = 0; j < 4; ++j)
            acc[j] = __builtin_amdgcn_mfma_f32_16x16x32_bf16(w1f[j], af, bias1v[j], 0, 0, 0);

        f32x4 oacc = oinit;
#pragma unroll
        for (int j = 0; j < 4; ++j) {
            bs4 pf;
            pf[0] = f2bf(fmaxf(acc[j][0], 0.0f));
            pf[1] = f2bf(fmaxf(acc[j][1], 0.0f));
            pf[2] = f2bf(fmaxf(acc[j][2], 0.0f));
            pf[3] = f2bf(fmaxf(acc[j][3], 0.0f));
            oacc = MFMA16(w2tf[j], pf, oacc);
        }

        const float r0 = __builtin_amdgcn_rcpf(1.0f + __expf(-oacc[0]));
        const float r1 = __builtin_amdgcn_rcpf(1.0f + __expf(-oacc[1]));
        const float r2 = __builtin_amdgcn_rcpf(1.0f + __expf(-oacc[2]));
        const float dv = oacc[3];
        const float dn = fmaxf(dv, 0.0f) + __logf(1.0f + __expf(-fabsf(dv)));

        if (g == 0) {
            const int s = sbase + row;
            float* rp = out + (size_t)s * 3;
            __builtin_nontemporal_store(r0, rp);
            __builtin_nontemporal_store(r1, rp + 1);
            __builtin_nontemporal_store(r2, rp + 2);
            __builtin_nontemporal_store(dn, out + dns_base + s);
        }
    };

    // ---- 3-stage pipeline: pos(t+2) || gather(t+1) || compute(t) ----
    float pxA, pyA, pzA, pxB, pyB, pzB;
    f32x4 gA0, gA1, gB0, gB1;
    loadpos(0, pxA, pyA, pzA);
    loadpos(1, pxB, pyB, pzB);
    issue_gather(pxA, pyA, pzA, gA0, gA1);

    for (int t = 0; t < NT; t += 2) {
        loadpos(t + 2, pxA, pyA, pzA);
        issue_gather(pxB, pyB, pzB, gB0, gB1);
        compute(chunk + t * 16, gA0, gA1);

        loadpos(t + 3, pxB, pyB, pzB);
        issue_gather(pxA, pyA, pzA, gA0, gA1);
        compute(chunk + (t + 1) * 16, gB0, gB1);
    }
}

extern "C" void kernel_launch(void* const* d_in, const int* in_sizes, int n_in,
                              void* d_out, int out_size, void* d_ws, size_t ws_size,
                              hipStream_t stream) {
    const float* pos   = (const float*)d_in[0];
    const float* table = (const float*)d_in[1];
    const float* W1    = (const float*)d_in[2];
    const float* b1    = (const float*)d_in[3];
    const float* W2    = (const float*)d_in[4];
    const float* b2    = (const float*)d_in[5];
    float* out = (float*)d_out;

    const int batch  = in_sizes[0] / 3;            // 4,194,304
    const int blocks = batch / (4 * NT * 16);      // 4096
    hipLaunchKernelGGL(plen_fused, dim3(blocks), dim3(256), 0, stream,
                       pos, table, W1, b1, W2, b2, out, batch);
}

// Round 7
// 118.972 us; speedup vs baseline: 1.7887x; 1.7887x over previous
//
#include <hip/hip_runtime.h>
#include <hip/hip_bf16.h>

typedef __attribute__((ext_vector_type(8))) short bs8;
typedef __attribute__((ext_vector_type(4))) short bs4;
typedef __attribute__((ext_vector_type(4))) float f32x4;

#define HID 64
#define FEATN 32
#define NT 16   // tiles of 16 samples per wave

static __device__ __forceinline__ short f2bf(float f) {
    __hip_bfloat16 h = __float2bfloat16(f);
    return __builtin_bit_cast(short, h);
}

#if defined(__HIP_DEVICE_COMPILE__)
#define MFMA16(a, b, c) __builtin_amdgcn_mfma_f32_16x16x16bf16_1k(a, b, c, 0, 0, 0)
#else
#define MFMA16(a, b, c) (c)
#endif

// Layer 1 (transposed): h^T = W1^T x feats^T via 4x mfma_f32_16x16x32_bf16.
// k-PERMUTED fragments for 64B-contiguous gather sectors:
//   load A: lane(g,row) reads row bytes [16g,16g+16)   -> k = 4g..4g+3
//   load B: lane(g,row) reads row bytes [64+16g,+16)   -> k = 16+4g..16+4g+3
// so each instruction covers bytes [0,64) resp. [64,128) of a row contiguously
// (2 x 64B sector requests per row instead of 8 x 16B scattered).
// W1 fragment uses the IDENTICAL k permutation (kdata = i<4 ? 4g+i : 12+4g+i),
// so the MFMA dot-product still sums each k exactly once.
// Layer 2: 4 chained mfma_16x16x16_bf16 with A = W2^T (rows>=4 zero),
// b2 in C-init; outputs land on g==0 lanes.
__global__ __launch_bounds__(256, 4) void plen_fused(
    const float* __restrict__ pos,
    const float* __restrict__ table,
    const float* __restrict__ W1,
    const float* __restrict__ b1,
    const float* __restrict__ W2,
    const float* __restrict__ b2,
    float* __restrict__ out,
    int batch)
{
    const int lane = threadIdx.x & 63;
    const int row  = lane & 15;
    const int g    = lane >> 4;

    // ---- static weight fragments (k-permuted to match gather layout) ----
    bs8   w1f[4];
    f32x4 bias1v[4];
    bs4   w2tf[4];
#pragma unroll
    for (int j = 0; j < 4; ++j) {
#pragma unroll
        for (int i = 0; i < 8; ++i) {
            const int kdata = (i < 4) ? (4 * g + i) : (12 + 4 * g + i);
            w1f[j][i] = f2bf(W1[kdata * HID + j * 16 + row]);
        }
        bias1v[j] = *(const f32x4*)(b1 + j * 16 + g * 4);
#pragma unroll
        for (int i = 0; i < 4; ++i)
            w2tf[j][i] = (row < 4) ? f2bf(W2[(j * 16 + g * 4 + i) * 4 + row]) : (short)0;
    }
    f32x4 oinit;
    if (g == 0) oinit = *(const f32x4*)b2;
    else        oinit = (f32x4){0.f, 0.f, 0.f, 0.f};

    const int wave_id = blockIdx.x * 4 + (threadIdx.x >> 6);
    const int chunk   = wave_id * (NT * 16);
    const size_t dns_base = (size_t)batch * 3;

    auto loadpos = [&](int t, float& x, float& y, float& z) {
        const int tt = t < NT ? t : NT - 1;          // clamp redundant prefetch
        const float* pp = pos + (size_t)(chunk + tt * 16 + row) * 3;
        x = pp[0]; y = pp[1]; z = pp[2];
    };
    auto issue_gather = [&](float x, float y, float z, f32x4& A, f32x4& B) {
        const unsigned ix = (unsigned)(int)(x * 128.0f);
        const unsigned iy = (unsigned)(int)(y * 128.0f);
        const unsigned iz = (unsigned)(int)(z * 128.0f);
        const unsigned flat = (ix << 14) | (iy << 7) | iz;
        const float* rp = table + (size_t)flat * FEATN;
        A = *(const f32x4*)(rp + 4 * g);             // bytes [16g, 16g+16)
        B = *(const f32x4*)(rp + 16 + 4 * g);        // bytes [64+16g, 64+16g+16)
    };
    auto compute = [&](int sbase, f32x4 f0, f32x4 f1) {
        bs8 af;
        af[0] = f2bf(f0[0]); af[1] = f2bf(f0[1]);
        af[2] = f2bf(f0[2]); af[3] = f2bf(f0[3]);
        af[4] = f2bf(f1[0]); af[5] = f2bf(f1[1]);
        af[6] = f2bf(f1[2]); af[7] = f2bf(f1[3]);

        f32x4 acc[4];
#pragma unroll
        for (int j = 0; j < 4; ++j)
            acc[j] = __builtin_amdgcn_mfma_f32_16x16x32_bf16(w1f[j], af, bias1v[j], 0, 0, 0);

        f32x4 oacc = oinit;
#pragma unroll
        for (int j = 0; j < 4; ++j) {
            bs4 pf;
            pf[0] = f2bf(fmaxf(acc[j][0], 0.0f));
            pf[1] = f2bf(fmaxf(acc[j][1], 0.0f));
            pf[2] = f2bf(fmaxf(acc[j][2], 0.0f));
            pf[3] = f2bf(fmaxf(acc[j][3], 0.0f));
            oacc = MFMA16(w2tf[j], pf, oacc);
        }

        const float r0 = __builtin_amdgcn_rcpf(1.0f + __expf(-oacc[0]));
        const float r1 = __builtin_amdgcn_rcpf(1.0f + __expf(-oacc[1]));
        const float r2 = __builtin_amdgcn_rcpf(1.0f + __expf(-oacc[2]));
        const float dv = oacc[3];
        const float dn = fmaxf(dv, 0.0f) + __logf(1.0f + __expf(-fabsf(dv)));

        if (g == 0) {
            const int s = sbase + row;
            float* rp = out + (size_t)s * 3;
            __builtin_nontemporal_store(r0, rp);
            __builtin_nontemporal_store(r1, rp + 1);
            __builtin_nontemporal_store(r2, rp + 2);
            __builtin_nontemporal_store(dn, out + dns_base + s);
        }
    };

    // ---- 3-stage pipeline: pos(t+2) || gather(t+1) || compute(t) ----
    float pxA, pyA, pzA, pxB, pyB, pzB;
    f32x4 gA0, gA1, gB0, gB1;
    loadpos(0, pxA, pyA, pzA);
    loadpos(1, pxB, pyB, pzB);
    issue_gather(pxA, pyA, pzA, gA0, gA1);

    for (int t = 0; t < NT; t += 2) {
        loadpos(t + 2, pxA, pyA, pzA);
        issue_gather(pxB, pyB, pzB, gB0, gB1);
        compute(chunk + t * 16, gA0, gA1);

        loadpos(t + 3, pxB, pyB, pzB);
        issue_gather(pxA, pyA, pzA, gA0, gA1);
        compute(chunk + (t + 1) * 16, gB0, gB1);
    }
}

extern "C" void kernel_launch(void* const* d_in, const int* in_sizes, int n_in,
                              void* d_out, int out_size, void* d_ws, size_t ws_size,
                              hipStream_t stream) {
    const float* pos   = (const float*)d_in[0];
    const float* table = (const float*)d_in[1];
    const float* W1    = (const float*)d_in[2];
    const float* b1    = (const float*)d_in[3];
    const float* W2    = (const float*)d_in[4];
    const float* b2    = (const float*)d_in[5];
    float* out = (float*)d_out;

    const int batch  = in_sizes[0] / 3;            // 4,194,304
    const int blocks = batch / (4 * NT * 16);      // 4096
    hipLaunchKernelGGL(plen_fused, dim3(blocks), dim3(256), 0, stream,
                       pos, table, W1, b1, W2, b2, out, batch);
}